// Round 9
// baseline (312.568 us; speedup 1.0000x reference)
//
#include <hip/hip_runtime.h>
#include <hip/hip_bf16.h>

#define DMODEL 1024
#define SEQ    2048
#define NB     2
#define NH     16
#define DKH    64

typedef __attribute__((ext_vector_type(4)))  float  f32x4;
typedef __attribute__((ext_vector_type(16))) float  f32x16;
typedef __attribute__((ext_vector_type(8)))  __bf16 bf16x8;
typedef __attribute__((ext_vector_type(8)))  short  short8;
typedef __attribute__((ext_vector_type(4)))  short  short4v;
typedef __attribute__((ext_vector_type(4)))  unsigned int uint4v;

__device__ __forceinline__ short f2bf(float f) {
    __bf16 b = (__bf16)f;
    return __builtin_bit_cast(short, b);
}

__device__ __forceinline__ f32x4 mfma16(short8 a, short8 b, f32x4 c) {
    return __builtin_amdgcn_mfma_f32_16x16x32_bf16(
        __builtin_bit_cast(bf16x8, a), __builtin_bit_cast(bf16x8, b), c, 0, 0, 0);
}

__device__ __forceinline__ f32x16 mfma32(short8 a, short8 b, f32x16 c) {
    return __builtin_amdgcn_mfma_f32_32x32x16_bf16(
        __builtin_bit_cast(bf16x8, a), __builtin_bit_cast(bf16x8, b), c, 0, 0, 0);
}

// pack two f32 -> one dword of 2 bf16
__device__ __forceinline__ unsigned int packbf(float a, float b) {
    unsigned int lo = (unsigned short)f2bf(a);
    unsigned int hi = (unsigned short)f2bf(b);
    return lo | (hi << 16);
}

// v_permlane32_swap_b32: a[32:63] <-> b[0:31]
__device__ __forceinline__ void swap32(unsigned int& a, unsigned int& b) {
    asm volatile("v_permlane32_swap_b32 %0, %1" : "+v"(a), "+v"(b));
}

// async global->LDS, 16B per lane (dest = wave-uniform base + lane*16)
__device__ __forceinline__ void async16(const void* gptr, void* lptr) {
    __builtin_amdgcn_global_load_lds(
        (const __attribute__((address_space(1))) void*)gptr,
        (__attribute__((address_space(3))) void*)lptr, 16, 0, 0);
}

// ---------------------------------------------------------------------------
// Prep (fused): bid<12288 -> Q/K/V fp32->bf16; else -> W transpose+cast.
// ---------------------------------------------------------------------------
__global__ __launch_bounds__(256) void prep_kernel(
    const float* __restrict__ Q, const float* __restrict__ K,
    const float* __restrict__ V,
    const float* __restrict__ W0, const float* __restrict__ W1,
    const float* __restrict__ W2, const float* __restrict__ W3,
    short* __restrict__ xb, short* __restrict__ WT) {
    __shared__ float tile[32][33];
    const int bid = blockIdx.x;
    if (bid < 12288) {
        const int z = bid >> 12;
        const float* src = (z == 0) ? Q : (z == 1) ? K : V;
        size_t i = (size_t)(bid & 4095) * 256 + threadIdx.x;  // float4 idx, 1M/input
        float4 v = ((const float4*)src)[i];
        short4v s;
        s[0] = f2bf(v.x); s[1] = f2bf(v.y); s[2] = f2bf(v.z); s[3] = f2bf(v.w);
        ((short4v*)(xb + (size_t)z * (NB * SEQ) * DMODEL))[i] = s;
    } else {
        const int t = bid - 12288;
        const int z = t >> 10, tt = t & 1023;
        const float* W = (z == 0) ? W0 : (z == 1) ? W1 : (z == 2) ? W2 : W3;
        short* o = WT + (size_t)z * DMODEL * DMODEL;
        const int k0 = (tt & 31) * 32, n0 = (tt >> 5) * 32;
        const int c = threadIdx.x & 31, r8 = threadIdx.x >> 5;
#pragma unroll
        for (int rr = 0; rr < 4; ++rr) {
            int row = r8 + 8 * rr;
            tile[row][c] = W[(size_t)(k0 + row) * DMODEL + n0 + c];
        }
        __syncthreads();
#pragma unroll
        for (int rr = 0; rr < 4; ++rr) {
            int n = r8 + 8 * rr;
            o[(size_t)(n0 + n) * DMODEL + k0 + c] = f2bf(tile[c][n]);
        }
    }
}

// ---------------------------------------------------------------------------
// m97-style NT GEMM core: 128x128 tile, BK=64, global_load_lds(16B) staging,
// 4 waves (2x2), each wave 64x64 out = 4x4 fragments of 16x16x32.
// ---------------------------------------------------------------------------
__device__ __forceinline__ void gemm128_core(
    const short* __restrict__ A, const short* __restrict__ BT,
    int i0, int n0, short (*A_lds)[64], short (*B_lds)[64], f32x4 acc[4][4]) {
    const int tid = threadIdx.x, lane = tid & 63, w = tid >> 6;
    const int wrow = w >> 1, wcol = w & 1, g = lane >> 4, qi = lane & 15;
    const int srow = lane >> 3, scol = (lane & 7) * 8;  // staging: lane covers 16B

    for (int k0 = 0; k0 < DMODEL; k0 += 64) {
#pragma unroll
        for (int i = 0; i < 4; ++i) {
            int t = w * 4 + i;  // 1KB chunk = 8 rows of 64 bf16
            async16(A  + (size_t)(i0 + 8 * t + srow) * DMODEL + k0 + scol, &A_lds[8 * t][0]);
            async16(BT + (size_t)(n0 + 8 * t + srow) * DMODEL + k0 + scol, &B_lds[8 * t][0]);
        }
        __syncthreads();
#pragma unroll
        for (int kc = 0; kc < 2; ++kc) {
            short8 a[4], b[4];
#pragma unroll
            for (int mt = 0; mt < 4; ++mt)
                a[mt] = *(const short8*)&A_lds[wrow * 64 + mt * 16 + qi][kc * 32 + g * 8];
#pragma unroll
            for (int nt = 0; nt < 4; ++nt)
                b[nt] = *(const short8*)&B_lds[wcol * 64 + nt * 16 + qi][kc * 32 + g * 8];
#pragma unroll
            for (int mt = 0; mt < 4; ++mt)
#pragma unroll
                for (int nt = 0; nt < 4; ++nt)
                    acc[mt][nt] = mfma16(a[mt], b[nt], acc[mt][nt]);
        }
        __syncthreads();
    }
}

// ---------------------------------------------------------------------------
// QKV projection: z=0 q (scaled by log2e/sqrt(dk)), z=1 k -> [B,H,S,Dk];
// z=2 v -> [B,H,Dk,S]
// ---------------------------------------------------------------------------
__global__ __launch_bounds__(256) void qkv_gemm_kernel(
    const short* __restrict__ xb, const short* __restrict__ WT,
    const float* __restrict__ bq, const float* __restrict__ bk,
    const float* __restrict__ bv,
    short* __restrict__ q_out, short* __restrict__ k_out, short* __restrict__ vT_out) {
    __shared__ __align__(16) short lds[128 * 128];
    short (*A_lds)[64]  = (short(*)[64])lds;
    short (*B_lds)[64]  = (short(*)[64])(lds + 128 * 64);
    short (*C_lds)[128] = (short(*)[128])lds;

    const int z = blockIdx.z;
    const short* A  = xb + (size_t)z * (NB * SEQ) * DMODEL;
    const short* BT = WT + (size_t)z * DMODEL * DMODEL;
    const float* bias = (z == 0) ? bq : (z == 1) ? bk : bv;
    // fold 1/sqrt(64) * log2(e) into q so attn softmax runs in exp2 domain
    const float scale = (z == 0) ? 0.125f * 1.44269504f : 1.0f;
    const int i0 = blockIdx.x * 128, n0 = blockIdx.y * 128;
    const int tid = threadIdx.x, lane = tid & 63, w = tid >> 6;
    const int wrow = w >> 1, wcol = w & 1, g = lane >> 4, qi = lane & 15;

    f32x4 acc[4][4];
#pragma unroll
    for (int mt = 0; mt < 4; ++mt)
#pragma unroll
        for (int nt = 0; nt < 4; ++nt) acc[mt][nt] = f32x4{0.f, 0.f, 0.f, 0.f};

    gemm128_core(A, BT, i0, n0, A_lds, B_lds, acc);

    // epilogue: bias+scale -> bf16 -> LDS repack ([i][n] for q/k, [n][i] for v)
#pragma unroll
    for (int mt = 0; mt < 4; ++mt)
#pragma unroll
        for (int nt = 0; nt < 4; ++nt) {
            int nl = wcol * 64 + nt * 16 + qi;
            float bb = bias[n0 + nl];
#pragma unroll
            for (int r = 0; r < 4; ++r) {
                int il = wrow * 64 + mt * 16 + 4 * g + r;
                short v = f2bf((acc[mt][nt][r] + bb) * scale);
                if (z == 2) C_lds[nl][il] = v;
                else        C_lds[il][nl] = v;
            }
        }
    __syncthreads();
    const int b = i0 >> 11, s0 = i0 & 2047;
#pragma unroll
    for (int rr = 0; rr < 8; ++rr) {
        int c = tid + 256 * rr;              // 2048 chunks of 8 shorts
        int row = c >> 4, off = (c & 15) * 8;
        short8 v8 = *(const short8*)&C_lds[row][off];
        if (z == 2) {  // row = n-local (head,d), off over s
            int h = (n0 + row) >> 6, d = (n0 + row) & 63;
            *(short8*)(vT_out + ((size_t)(b * NH + h) * DKH + d) * SEQ + s0 + off) = v8;
        } else {       // row = s-local, off over n (head,d)
            int h = (n0 + off) >> 6, d = (n0 + off) & 63;
            short* outp = (z == 0) ? q_out : k_out;
            *(short8*)(outp + ((size_t)(b * NH + h) * SEQ + (s0 + row)) * DKH + d) = v8;
        }
    }
}

// ---------------------------------------------------------------------------
// Flash attention v3: v2 structure (32x32 MFMA, direct L2 reads, in-register
// P via permlane32_swap) + bijective XCD swizzle (4 bh per XCD -> 2MB L2-
// resident K/V) + key-split x2 (warp = (qw, kvh); 16 waves/CU) with exact
// flash merge through LDS at the end.
// Grid: 1024 blocks x 256 thr. Q pre-scaled by log2e/sqrt(Dk).
// ---------------------------------------------------------------------------
__global__ __launch_bounds__(256, 4) void attn_kernel(
    const short* __restrict__ q_ws, const short* __restrict__ k_ws,
    const short* __restrict__ vT_ws, short* __restrict__ attn_out) {
    __shared__ __align__(16) float o_xch[2][64][36];   // 18KB, +pad vs 32
    __shared__ float ml_xch[2][32][2];
    __shared__ float bca[2][32], bcb[2][32];
    __shared__ float fct_lds[4][32];

    // bijective XCD swizzle: each XCD (lin&7) owns 4 consecutive bh
    const int lin = blockIdx.x;
    const int xcd = lin & 7, idx = lin >> 3;     // idx in [0,128)
    const int bh  = xcd * 4 + (idx & 3);         // 4 bh per XCD
    const int qt  = idx >> 2;                    // 32 q-tiles of 64

    const int tid = threadIdx.x, lane = tid & 63, w = tid >> 6;
    const int l31 = lane & 31, hi = lane >> 5;
    const int qw = w >> 1, kvh = w & 1;          // q-subtile, kv-half
    const int q0w = qt * 64 + qw * 32;
    const short* qg = q_ws + (size_t)bh * SEQ * DKH;
    const short* kg = k_ws + (size_t)bh * SEQ * DKH;
    const short* vg = vT_ws + (size_t)bh * DKH * SEQ;

    // Q B-frags (col = query = l31, k = c*16 + hi*8 + e), live whole kernel
    short8 qf[4];
#pragma unroll
    for (int c = 0; c < 4; ++c)
        qf[c] = *(const short8*)(qg + (size_t)(q0w + l31) * DKH + c * 16 + hi * 8);

    // per-lane base pointers for K (A-frags) and V^T (B-frags)
    const short* krow = kg + (size_t)l31 * DKH + hi * 8;
    const short* vrow = vg + (size_t)l31 * SEQ + hi * 8;

    f32x16 o0, o1;
#pragma unroll
    for (int e = 0; e < 16; ++e) { o0[e] = 0.f; o1[e] = 0.f; }
    float m_run = -1e30f, l_run = 0.f;

    const int jbase = kvh * (SEQ / 2);
    for (int j0 = jbase; j0 < jbase + SEQ / 2; j0 += 64) {
        // ---- QK^T: two 32-key subtiles, K-dim 64 = 4 mfma each ----
        f32x16 st0, st1;
#pragma unroll
        for (int e = 0; e < 16; ++e) { st0[e] = 0.f; st1[e] = 0.f; }
        __builtin_amdgcn_s_setprio(1);
#pragma unroll
        for (int c = 0; c < 4; ++c) {
            short8 a0 = *(const short8*)(krow + (size_t)(j0)      * DKH + c * 16);
            short8 a1 = *(const short8*)(krow + (size_t)(j0 + 32) * DKH + c * 16);
            st0 = mfma32(a0, qf[c], st0);
            st1 = mfma32(a1, qf[c], st1);
        }
        __builtin_amdgcn_s_setprio(0);

        // ---- softmax (lane = query, 32 scores split across lane halves) ----
        float pmax = fmaxf(st0[0], st1[0]);
#pragma unroll
        for (int r = 1; r < 16; ++r) pmax = fmaxf(pmax, fmaxf(st0[r], st1[r]));
        pmax = fmaxf(pmax, __shfl_xor(pmax, 32));

        float m_new = m_run, fct = 1.0f;
        const int need = !__all(pmax <= m_run + 11.54f);  // defer-max, exp2 domain
        if (need) {
            m_new = fmaxf(m_run, pmax);
            fct = exp2f(m_run - m_new);
            if (lane < 32) fct_lds[w][l31] = fct;  // query-indexed broadcast
        }

        float p0[16], p1[16], lsum = 0.f;
#pragma unroll
        for (int r = 0; r < 16; ++r) {
            p0[r] = exp2f(st0[r] - m_new);
            p1[r] = exp2f(st1[r] - m_new);
            lsum += p0[r] + p1[r];
        }
        lsum += __shfl_xor(lsum, 32);
        l_run = l_run * fct + lsum;
        m_run = m_new;

        // ---- P -> bf16 A-frags in-register (pack + permlane32_swap) ----
        unsigned int pw0[8], pw1[8];
#pragma unroll
        for (int j = 0; j < 8; ++j) {
            pw0[j] = packbf(p0[2 * j], p0[2 * j + 1]);
            pw1[j] = packbf(p1[2 * j], p1[2 * j + 1]);
        }
        swap32(pw0[0], pw0[2]); swap32(pw0[1], pw0[3]);
        swap32(pw0[4], pw0[6]); swap32(pw0[5], pw0[7]);
        swap32(pw1[0], pw1[2]); swap32(pw1[1], pw1[3]);
        swap32(pw1[4], pw1[6]); swap32(pw1[5], pw1[7]);

        short8 pa[4];
        {
            uint4v u;
            u[0] = pw0[0]; u[1] = pw0[1]; u[2] = pw0[2]; u[3] = pw0[3];
            pa[0] = __builtin_bit_cast(short8, u);
            u[0] = pw0[4]; u[1] = pw0[5]; u[2] = pw0[6]; u[3] = pw0[7];
            pa[1] = __builtin_bit_cast(short8, u);
            u[0] = pw1[0]; u[1] = pw1[1]; u[2] = pw1[2]; u[3] = pw1[3];
            pa[2] = __builtin_bit_cast(short8, u);
            u[0] = pw1[4]; u[1] = pw1[5]; u[2] = pw1[6]; u[3] = pw1[7];
            pa[3] = __builtin_bit_cast(short8, u);
        }

        // ---- O rescale (query-index -> C/D-row-index via LDS broadcast) ----
        if (need) {
            f32x4 fr[4];
#pragma unroll
            for (int u2 = 0; u2 < 4; ++u2)
                fr[u2] = *(const f32x4*)&fct_lds[w][8 * u2 + 4 * hi];
#pragma unroll
            for (int r = 0; r < 16; ++r) {
                float f = fr[r >> 2][r & 3];
                o0[r] *= f; o1[r] *= f;
            }
        }

        // ---- PV: O[query][d], d-blocks 0/1, 4 k-frags over 64 keys ----
        __builtin_amdgcn_s_setprio(1);
#pragma unroll
        for (int kk = 0; kk < 4; ++kk) {
            short8 b0 = *(const short8*)(vrow + j0 + kk * 16);
            short8 b1 = *(const short8*)(vrow + (size_t)32 * SEQ + j0 + kk * 16);
            o0 = mfma32(pa[kk], b0, o0);
            o1 = mfma32(pa[kk], b1, o1);
        }
        __builtin_amdgcn_s_setprio(0);
    }

    // ---- merge the two kv-halves (exact flash combine), then store ----
    if (kvh == 1) {
        if (lane < 32) { ml_xch[qw][l31][0] = m_run; ml_xch[qw][l31][1] = l_run; }
#pragma unroll
        for (int r = 0; r < 16; ++r) {
            o_xch[qw][lane][r]      = o0[r];
            o_xch[qw][lane][16 + r] = o1[r];
        }
    }
    __syncthreads();
    if (kvh == 0) {
        float m1 = ml_xch[qw][l31][0], l1 = ml_xch[qw][l31][1];
        float mstar = fmaxf(m_run, m1);
        float a = exp2f(m_run - mstar), bb = exp2f(m1 - mstar);
        float linv = 1.0f / (a * l_run + bb * l1);
        if (lane < 32) { bca[qw][l31] = a * linv; bcb[qw][l31] = bb * linv; }
        f32x4 fa[4], fb[4];
#pragma unroll
        for (int u2 = 0; u2 < 4; ++u2) {
            fa[u2] = *(const f32x4*)&bca[qw][8 * u2 + 4 * hi];
            fb[u2] = *(const f32x4*)&bcb[qw][8 * u2 + 4 * hi];
        }
        const int b = bh >> 4, h = bh & 15;
#pragma unroll
        for (int r = 0; r < 16; ++r) {
            float wa = fa[r >> 2][r & 3], wb = fb[r >> 2][r & 3];
            float v0 = wa * o0[r] + wb * o_xch[qw][lane][r];
            float v1 = wa * o1[r] + wb * o_xch[qw][lane][16 + r];
            int spos = q0w + (r & 3) + 8 * (r >> 2) + 4 * hi;
            size_t base = (size_t)(b * SEQ + spos) * DMODEL + h * 64 + l31;
            attn_out[base]      = f2bf(v0);
            attn_out[base + 32] = f2bf(v1);
        }
    }
}

// ---------------------------------------------------------------------------
// Output projection: 128x64 tile (512 blocks -> 2/CU), bf16 NT GEMM -> fp32+bias
// 4 waves stacked on M; per-wave 32x64 out = 2x4 fragments.
// ---------------------------------------------------------------------------
__global__ __launch_bounds__(256) void oproj_kernel(
    const short* __restrict__ attn, const short* __restrict__ WoT,
    const float* __restrict__ bo, float* __restrict__ out) {
    __shared__ __align__(16) short A_lds[128][64];  // 16 KB
    __shared__ __align__(16) short B_lds[64][64];   // 8 KB
    const int i0 = blockIdx.x * 128, n0 = blockIdx.y * 64;
    const int tid = threadIdx.x, lane = tid & 63, w = tid >> 6;
    const int g = lane >> 4, qi = lane & 15;
    const int srow = lane >> 3, scol = (lane & 7) * 8;

    f32x4 acc[2][4];
#pragma unroll
    for (int mt = 0; mt < 2; ++mt)
#pragma unroll
        for (int nt = 0; nt < 4; ++nt) acc[mt][nt] = f32x4{0.f, 0.f, 0.f, 0.f};

    for (int k0 = 0; k0 < DMODEL; k0 += 64) {
#pragma unroll
        for (int i = 0; i < 4; ++i) {
            int t = w * 4 + i;  // A: 16 chunks of 8 rows
            async16(attn + (size_t)(i0 + 8 * t + srow) * DMODEL + k0 + scol, &A_lds[8 * t][0]);
        }
#pragma unroll
        for (int i = 0; i < 2; ++i) {
            int t = w * 2 + i;  // B: 8 chunks of 8 rows
            async16(WoT + (size_t)(n0 + 8 * t + srow) * DMODEL + k0 + scol, &B_lds[8 * t][0]);
        }
        __syncthreads();
#pragma unroll
        for (int kc = 0; kc < 2; ++kc) {
            short8 a[2], b[4];
#pragma unroll
            for (int mt = 0; mt < 2; ++mt)
                a[mt] = *(const short8*)&A_lds[w * 32 + mt * 16 + qi][kc * 32 + g * 8];
#pragma unroll
            for (int nt = 0; nt < 4; ++nt)
                b[nt] = *(const short8*)&B_lds[nt * 16 + qi][kc * 32 + g * 8];
#pragma unroll
            for (int mt = 0; mt < 2; ++mt)
#pragma unroll
                for (int nt = 0; nt < 4; ++nt)
                    acc[mt][nt] = mfma16(a[mt], b[nt], acc[mt][nt]);
        }
        __syncthreads();
    }

#pragma unroll
    for (int mt = 0; mt < 2; ++mt)
#pragma unroll
        for (int nt = 0; nt < 4; ++nt) {
            int ncol = n0 + nt * 16 + qi;
            float bb = bo[ncol];
#pragma unroll
            for (int r = 0; r < 4; ++r) {
                int i = i0 + w * 32 + mt * 16 + 4 * g + r;
                out[(size_t)i * DMODEL + ncol] = acc[mt][nt][r] + bb;
            }
        }
}

// ---------------------------------------------------------------------------
extern "C" void kernel_launch(void* const* d_in, const int* in_sizes, int n_in,
                              void* d_out, int out_size, void* d_ws, size_t ws_size,
                              hipStream_t stream) {
    const float* Q  = (const float*)d_in[0];
    const float* K  = (const float*)d_in[1];
    const float* V  = (const float*)d_in[2];
    const float* Wq = (const float*)d_in[3];
    const float* bq = (const float*)d_in[4];
    const float* Wk = (const float*)d_in[5];
    const float* bk = (const float*)d_in[6];
    const float* Wv = (const float*)d_in[7];
    const float* bv = (const float*)d_in[8];
    const float* Wo = (const float*)d_in[9];
    const float* bo = (const float*)d_in[10];

    // ws layout (shorts): WT[4M] | q[4M] | k[4M] | vT[4M] | xb[12M]
    // attn output reuses the xb region (xb consumed by qkv_gemm before attn runs)
    const size_t WSZ = (size_t)DMODEL * DMODEL;      // 1M
    const size_t XSZ = (size_t)NB * SEQ * DMODEL;    // 4M
    if (ws_size < (4 * WSZ + 6 * XSZ) * sizeof(short)) return;  // 56 MB

    short* WT      = (short*)d_ws;
    short* q_ws    = WT + 4 * WSZ;
    short* k_ws    = q_ws + XSZ;
    short* vT_ws   = k_ws + XSZ;
    short* xb      = vT_ws + XSZ;
    short* attn_ws = xb;  // reuse

    prep_kernel<<<dim3(12288 + 4096), 256, 0, stream>>>(
        Q, K, V, Wq, Wk, Wv, Wo, xb, WT);
    qkv_gemm_kernel<<<dim3((NB * SEQ) / 128, DMODEL / 128, 3), 256, 0, stream>>>(
        xb, WT, bq, bk, bv, q_ws, k_ws, vT_ws);
    attn_kernel<<<dim3(1024), 256, 0, stream>>>(
        q_ws, k_ws, vT_ws, attn_ws);
    oproj_kernel<<<dim3((NB * SEQ) / 128, DMODEL / 64), 256, 0, stream>>>(
        attn_ws, WT + 3 * WSZ, bo, (float*)d_out);
}

// Round 11
// 263.365 us; speedup vs baseline: 1.1868x; 1.1868x over previous
//
#include <hip/hip_runtime.h>
#include <hip/hip_bf16.h>

#define DMODEL 1024
#define SEQ    2048
#define NB     2
#define NH     16
#define DKH    64

typedef __attribute__((ext_vector_type(4)))  float  f32x4;
typedef __attribute__((ext_vector_type(16))) float  f32x16;
typedef __attribute__((ext_vector_type(8)))  __bf16 bf16x8;
typedef __attribute__((ext_vector_type(8)))  short  short8;
typedef __attribute__((ext_vector_type(4)))  short  short4v;
typedef __attribute__((ext_vector_type(4)))  unsigned int uint4v;

__device__ __forceinline__ short f2bf(float f) {
    __bf16 b = (__bf16)f;
    return __builtin_bit_cast(short, b);
}

__device__ __forceinline__ f32x4 mfma16(short8 a, short8 b, f32x4 c) {
    return __builtin_amdgcn_mfma_f32_16x16x32_bf16(
        __builtin_bit_cast(bf16x8, a), __builtin_bit_cast(bf16x8, b), c, 0, 0, 0);
}

__device__ __forceinline__ f32x16 mfma32(short8 a, short8 b, f32x16 c) {
    return __builtin_amdgcn_mfma_f32_32x32x16_bf16(
        __builtin_bit_cast(bf16x8, a), __builtin_bit_cast(bf16x8, b), c, 0, 0, 0);
}

// pack two f32 -> one dword of 2 bf16
__device__ __forceinline__ unsigned int packbf(float a, float b) {
    unsigned int lo = (unsigned short)f2bf(a);
    unsigned int hi = (unsigned short)f2bf(b);
    return lo | (hi << 16);
}

// v_permlane32_swap_b32: a[32:63] <-> b[0:31]
__device__ __forceinline__ void swap32(unsigned int& a, unsigned int& b) {
    asm volatile("v_permlane32_swap_b32 %0, %1" : "+v"(a), "+v"(b));
}

// async global->LDS, 16B per lane (dest = wave-uniform base + lane*16)
__device__ __forceinline__ void async16(const void* gptr, void* lptr) {
    __builtin_amdgcn_global_load_lds(
        (const __attribute__((address_space(1))) void*)gptr,
        (__attribute__((address_space(3))) void*)lptr, 16, 0, 0);
}

// ---------------------------------------------------------------------------
// Prep (fused): bid<12288 -> Q/K/V fp32->bf16; else -> W transpose+cast.
// ---------------------------------------------------------------------------
__global__ __launch_bounds__(256) void prep_kernel(
    const float* __restrict__ Q, const float* __restrict__ K,
    const float* __restrict__ V,
    const float* __restrict__ W0, const float* __restrict__ W1,
    const float* __restrict__ W2, const float* __restrict__ W3,
    short* __restrict__ xb, short* __restrict__ WT) {
    __shared__ float tile[32][33];
    const int bid = blockIdx.x;
    if (bid < 12288) {
        const int z = bid >> 12;
        const float* src = (z == 0) ? Q : (z == 1) ? K : V;
        size_t i = (size_t)(bid & 4095) * 256 + threadIdx.x;  // float4 idx, 1M/input
        float4 v = ((const float4*)src)[i];
        short4v s;
        s[0] = f2bf(v.x); s[1] = f2bf(v.y); s[2] = f2bf(v.z); s[3] = f2bf(v.w);
        ((short4v*)(xb + (size_t)z * (NB * SEQ) * DMODEL))[i] = s;
    } else {
        const int t = bid - 12288;
        const int z = t >> 10, tt = t & 1023;
        const float* W = (z == 0) ? W0 : (z == 1) ? W1 : (z == 2) ? W2 : W3;
        short* o = WT + (size_t)z * DMODEL * DMODEL;
        const int k0 = (tt & 31) * 32, n0 = (tt >> 5) * 32;
        const int c = threadIdx.x & 31, r8 = threadIdx.x >> 5;
#pragma unroll
        for (int rr = 0; rr < 4; ++rr) {
            int row = r8 + 8 * rr;
            tile[row][c] = W[(size_t)(k0 + row) * DMODEL + n0 + c];
        }
        __syncthreads();
#pragma unroll
        for (int rr = 0; rr < 4; ++rr) {
            int n = r8 + 8 * rr;
            o[(size_t)(n0 + n) * DMODEL + k0 + c] = f2bf(tile[c][n]);
        }
    }
}

// ---------------------------------------------------------------------------
// m97-style NT GEMM core: 128x128 tile, BK=64, global_load_lds(16B) staging,
// 4 waves (2x2), each wave 64x64 out = 4x4 fragments of 16x16x32.
// ---------------------------------------------------------------------------
__device__ __forceinline__ void gemm128_core(
    const short* __restrict__ A, const short* __restrict__ BT,
    int i0, int n0, short (*A_lds)[64], short (*B_lds)[64], f32x4 acc[4][4]) {
    const int tid = threadIdx.x, lane = tid & 63, w = tid >> 6;
    const int wrow = w >> 1, wcol = w & 1, g = lane >> 4, qi = lane & 15;
    const int srow = lane >> 3, scol = (lane & 7) * 8;  // staging: lane covers 16B

    for (int k0 = 0; k0 < DMODEL; k0 += 64) {
#pragma unroll
        for (int i = 0; i < 4; ++i) {
            int t = w * 4 + i;  // 1KB chunk = 8 rows of 64 bf16
            async16(A  + (size_t)(i0 + 8 * t + srow) * DMODEL + k0 + scol, &A_lds[8 * t][0]);
            async16(BT + (size_t)(n0 + 8 * t + srow) * DMODEL + k0 + scol, &B_lds[8 * t][0]);
        }
        __syncthreads();
#pragma unroll
        for (int kc = 0; kc < 2; ++kc) {
            short8 a[4], b[4];
#pragma unroll
            for (int mt = 0; mt < 4; ++mt)
                a[mt] = *(const short8*)&A_lds[wrow * 64 + mt * 16 + qi][kc * 32 + g * 8];
#pragma unroll
            for (int nt = 0; nt < 4; ++nt)
                b[nt] = *(const short8*)&B_lds[wcol * 64 + nt * 16 + qi][kc * 32 + g * 8];
#pragma unroll
            for (int mt = 0; mt < 4; ++mt)
#pragma unroll
                for (int nt = 0; nt < 4; ++nt)
                    acc[mt][nt] = mfma16(a[mt], b[nt], acc[mt][nt]);
        }
        __syncthreads();
    }
}

// ---------------------------------------------------------------------------
// QKV projection: z=0 q (scaled by log2e/sqrt(dk)), z=1 k -> [B,H,S,Dk];
// z=2 v -> [B,H,Dk,S]
// ---------------------------------------------------------------------------
__global__ __launch_bounds__(256) void qkv_gemm_kernel(
    const short* __restrict__ xb, const short* __restrict__ WT,
    const float* __restrict__ bq, const float* __restrict__ bk,
    const float* __restrict__ bv,
    short* __restrict__ q_out, short* __restrict__ k_out, short* __restrict__ vT_out) {
    __shared__ __align__(16) short lds[128 * 128];
    short (*A_lds)[64]  = (short(*)[64])lds;
    short (*B_lds)[64]  = (short(*)[64])(lds + 128 * 64);
    short (*C_lds)[128] = (short(*)[128])lds;

    const int z = blockIdx.z;
    const short* A  = xb + (size_t)z * (NB * SEQ) * DMODEL;
    const short* BT = WT + (size_t)z * DMODEL * DMODEL;
    const float* bias = (z == 0) ? bq : (z == 1) ? bk : bv;
    // fold 1/sqrt(64) * log2(e) into q so attn softmax runs in exp2 domain
    const float scale = (z == 0) ? 0.125f * 1.44269504f : 1.0f;
    const int i0 = blockIdx.x * 128, n0 = blockIdx.y * 128;
    const int tid = threadIdx.x, lane = tid & 63, w = tid >> 6;
    const int wrow = w >> 1, wcol = w & 1, g = lane >> 4, qi = lane & 15;

    f32x4 acc[4][4];
#pragma unroll
    for (int mt = 0; mt < 4; ++mt)
#pragma unroll
        for (int nt = 0; nt < 4; ++nt) acc[mt][nt] = f32x4{0.f, 0.f, 0.f, 0.f};

    gemm128_core(A, BT, i0, n0, A_lds, B_lds, acc);

    // epilogue: bias+scale -> bf16 -> LDS repack ([i][n] for q/k, [n][i] for v)
#pragma unroll
    for (int mt = 0; mt < 4; ++mt)
#pragma unroll
        for (int nt = 0; nt < 4; ++nt) {
            int nl = wcol * 64 + nt * 16 + qi;
            float bb = bias[n0 + nl];
#pragma unroll
            for (int r = 0; r < 4; ++r) {
                int il = wrow * 64 + mt * 16 + 4 * g + r;
                short v = f2bf((acc[mt][nt][r] + bb) * scale);
                if (z == 2) C_lds[nl][il] = v;
                else        C_lds[il][nl] = v;
            }
        }
    __syncthreads();
    const int b = i0 >> 11, s0 = i0 & 2047;
#pragma unroll
    for (int rr = 0; rr < 8; ++rr) {
        int c = tid + 256 * rr;              // 2048 chunks of 8 shorts
        int row = c >> 4, off = (c & 15) * 8;
        short8 v8 = *(const short8*)&C_lds[row][off];
        if (z == 2) {  // row = n-local (head,d), off over s
            int h = (n0 + row) >> 6, d = (n0 + row) & 63;
            *(short8*)(vT_out + ((size_t)(b * NH + h) * DKH + d) * SEQ + s0 + off) = v8;
        } else {       // row = s-local, off over n (head,d)
            int h = (n0 + off) >> 6, d = (n0 + off) & 63;
            short* outp = (z == 0) ? q_out : k_out;
            *(short8*)(outp + ((size_t)(b * NH + h) * SEQ + (s0 + row)) * DKH + d) = v8;
        }
    }
}

// ---------------------------------------------------------------------------
// Flash attention v4: 32x32 MFMA + in-register softmax/P (from v2/v3) with
// LDS-staged K/V (from rounds 2-4) to kill VMEM transaction amplification.
// K/V tiles staged coalesced via global_load_lds with inverse-XOR-swizzled
// per-lane SOURCE (linear LDS dest, rule #21); fragment ds_reads use
// chunk ^ (row&7) -> 4-way conflicts instead of 32-way. Double-buffered,
// 1 barrier/tile. XCD swizzle: 4 bh per XCD (K/V L2-resident).
// Grid 512 x 256 thr; 4 waves x 32 queries. Q pre-scaled by log2e/sqrt(Dk).
// ---------------------------------------------------------------------------
__global__ __launch_bounds__(256, 2) void attn_kernel(
    const short* __restrict__ q_ws, const short* __restrict__ k_ws,
    const short* __restrict__ vT_ws, short* __restrict__ attn_out) {
    __shared__ __align__(16) short K_lds[2][4096];   // 64 keys x 64 shorts
    __shared__ __align__(16) short V_lds[2][4096];   // 64 d    x 64 shorts
    __shared__ float fct_lds[4][32];

    // bijective XCD swizzle: each XCD (lin&7) owns 4 consecutive bh
    const int lin = blockIdx.x;
    const int xcd = lin & 7, idx = lin >> 3;     // idx in [0,64)
    const int bh  = xcd * 4 + (idx & 3);
    const int qt  = idx >> 2;                    // 16 q-tiles of 128

    const int tid = threadIdx.x, lane = tid & 63, w = tid >> 6;
    const int l31 = lane & 31, hi = lane >> 5;
    const int q0w = qt * 128 + w * 32;
    const short* qg = q_ws + (size_t)bh * SEQ * DKH;
    const short* kg = k_ws + (size_t)bh * SEQ * DKH;
    const short* vg = vT_ws + (size_t)bh * DKH * SEQ;

    // Q B-frags (col = query = l31, k = c*16 + hi*8 + e), live whole kernel
    short8 qf[4];
#pragma unroll
    for (int c = 0; c < 4; ++c)
        qf[c] = *(const short8*)(qg + (size_t)(q0w + l31) * DKH + c * 16 + hi * 8);

    // staging geometry: instr i covers rows i*8..i*8+7; lane -> (row, phys chunk)
    // LDS phys chunk cp holds logical chunk cp ^ (row&7); row&7 == lane>>3 here.
    const int srow = lane >> 3;                       // 0..7 within instr
    const int scl  = (((lane & 7) ^ srow)) * 8;       // logical chunk offset (shorts)
    // wave roles: w<2 -> K (instrs w*4..w*4+3), w>=2 -> V ((w&1)*4..+3)
    auto STAGE = [&](int t, int buf) {
        const int j0 = t * 64;
        if (w < 2) {
            const short* kb = kg + (size_t)j0 * DKH;
#pragma unroll
            for (int i2 = 0; i2 < 4; ++i2) {
                int i = (w & 1) * 4 + i2;
                async16(kb + (size_t)(i * 8 + srow) * DKH + scl, &K_lds[buf][i * 512]);
            }
        } else {
#pragma unroll
            for (int i2 = 0; i2 < 4; ++i2) {
                int i = (w & 1) * 4 + i2;
                async16(vg + (size_t)(i * 8 + srow) * SEQ + j0 + scl, &V_lds[buf][i * 512]);
            }
        }
    };

    STAGE(0, 0);

    f32x16 o0, o1;
#pragma unroll
    for (int e = 0; e < 16; ++e) { o0[e] = 0.f; o1[e] = 0.f; }
    float m_run = -1e30f, l_run = 0.f;
    const int xswz = (l31 & 7);  // row&7 for this lane's fragment rows
    const int NT = SEQ / 64;

    for (int t = 0; t < NT; ++t) {
        const int cur = t & 1;
        __syncthreads();  // buf[cur] staged (vmcnt drained); prev reads done
        if (t + 1 < NT) STAGE(t + 1, cur ^ 1);

        // ---- QK^T: two 32-key subtiles, K-dim 64 = 4 mfma each ----
        f32x16 st0, st1;
#pragma unroll
        for (int e = 0; e < 16; ++e) { st0[e] = 0.f; st1[e] = 0.f; }
        __builtin_amdgcn_s_setprio(1);
#pragma unroll
        for (int c = 0; c < 4; ++c) {
            int cp = ((c * 2 + hi) ^ xswz) * 8;  // physical chunk (shorts)
            short8 a0 = *(const short8*)&K_lds[cur][l31 * 64 + cp];
            short8 a1 = *(const short8*)&K_lds[cur][(32 + l31) * 64 + cp];
            st0 = mfma32(a0, qf[c], st0);
            st1 = mfma32(a1, qf[c], st1);
        }
        __builtin_amdgcn_s_setprio(0);

        // ---- softmax (lane = query, 32 scores split across lane halves) ----
        float pm[16];
#pragma unroll
        for (int r = 0; r < 16; ++r) pm[r] = fmaxf(st0[r], st1[r]);
#pragma unroll
        for (int s2 = 8; s2 > 0; s2 >>= 1)
#pragma unroll
            for (int r = 0; r < s2; ++r) pm[r] = fmaxf(pm[r], pm[r + s2]);
        float pmax = fmaxf(pm[0], __shfl_xor(pm[0], 32));

        float m_new = m_run, fct = 1.0f;
        const int need = !__all(pmax <= m_run + 11.54f);  // defer-max, exp2 domain
        if (need) {
            m_new = fmaxf(m_run, pmax);
            fct = exp2f(m_run - m_new);
            if (lane < 32) fct_lds[w][l31] = fct;  // query-indexed broadcast
        }

        float p0[16], p1[16], lsum = 0.f;
#pragma unroll
        for (int r = 0; r < 16; ++r) {
            p0[r] = exp2f(st0[r] - m_new);
            p1[r] = exp2f(st1[r] - m_new);
            lsum += p0[r] + p1[r];
        }
        lsum += __shfl_xor(lsum, 32);
        l_run = l_run * fct + lsum;
        m_run = m_new;

        // ---- P -> bf16 A-frags in-register (pack + permlane32_swap) ----
        unsigned int pw0[8], pw1[8];
#pragma unroll
        for (int j = 0; j < 8; ++j) {
            pw0[j] = packbf(p0[2 * j], p0[2 * j + 1]);
            pw1[j] = packbf(p1[2 * j], p1[2 * j + 1]);
        }
        swap32(pw0[0], pw0[2]); swap32(pw0[1], pw0[3]);
        swap32(pw0[4], pw0[6]); swap32(pw0[5], pw0[7]);
        swap32(pw1[0], pw1[2]); swap32(pw1[1], pw1[3]);
        swap32(pw1[4], pw1[6]); swap32(pw1[5], pw1[7]);

        short8 pa[4];
        {
            uint4v u;
            u[0] = pw0[0]; u[1] = pw0[1]; u[2] = pw0[2]; u[3] = pw0[3];
            pa[0] = __builtin_bit_cast(short8, u);
            u[0] = pw0[4]; u[1] = pw0[5]; u[2] = pw0[6]; u[3] = pw0[7];
            pa[1] = __builtin_bit_cast(short8, u);
            u[0] = pw1[0]; u[1] = pw1[1]; u[2] = pw1[2]; u[3] = pw1[3];
            pa[2] = __builtin_bit_cast(short8, u);
            u[0] = pw1[4]; u[1] = pw1[5]; u[2] = pw1[6]; u[3] = pw1[7];
            pa[3] = __builtin_bit_cast(short8, u);
        }

        // ---- O rescale (query-index -> C/D-row-index via LDS broadcast) ----
        if (need) {
            f32x4 fr[4];
#pragma unroll
            for (int u2 = 0; u2 < 4; ++u2)
                fr[u2] = *(const f32x4*)&fct_lds[w][8 * u2 + 4 * hi];
#pragma unroll
            for (int r = 0; r < 16; ++r) {
                float f = fr[r >> 2][r & 3];
                o0[r] *= f; o1[r] *= f;
            }
        }

        // ---- PV: O[query][d], d-blocks 0/1, 4 k-frags over 64 keys ----
        __builtin_amdgcn_s_setprio(1);
#pragma unroll
        for (int kk = 0; kk < 4; ++kk) {
            int cp = ((kk * 2 + hi) ^ xswz) * 8;
            short8 b0 = *(const short8*)&V_lds[cur][l31 * 64 + cp];
            short8 b1 = *(const short8*)&V_lds[cur][(32 + l31) * 64 + cp];
            o0 = mfma32(pa[kk], b0, o0);
            o1 = mfma32(pa[kk], b1, o1);
        }
        __builtin_amdgcn_s_setprio(0);
    }

    // ---- epilogue: 1/l broadcast, normalize, store ----
    float linv = 1.0f / l_run;
    if (lane < 32) fct_lds[w][l31] = linv;
    f32x4 lr[4];
#pragma unroll
    for (int u2 = 0; u2 < 4; ++u2)
        lr[u2] = *(const f32x4*)&fct_lds[w][8 * u2 + 4 * hi];

    const int b = bh >> 4, h = bh & 15;
#pragma unroll
    for (int r = 0; r < 16; ++r) {
        float f = lr[r >> 2][r & 3];
        int spos = q0w + (r & 3) + 8 * (r >> 2) + 4 * hi;
        size_t base = (size_t)(b * SEQ + spos) * DMODEL + h * 64 + l31;
        attn_out[base]      = f2bf(o0[r] * f);
        attn_out[base + 32] = f2bf(o1[r] * f);
    }
}

// ---------------------------------------------------------------------------
// Output projection: 128x64 tile (512 blocks -> 2/CU), bf16 NT GEMM -> fp32+bias
// 4 waves stacked on M; per-wave 32x64 out = 2x4 fragments.
// ---------------------------------------------------------------------------
__global__ __launch_bounds__(256) void oproj_kernel(
    const short* __restrict__ attn, const short* __restrict__ WoT,
    const float* __restrict__ bo, float* __restrict__ out) {
    __shared__ __align__(16) short A_lds[128][64];  // 16 KB
    __shared__ __align__(16) short B_lds[64][64];   // 8 KB
    const int i0 = blockIdx.x * 128, n0 = blockIdx.y * 64;
    const int tid = threadIdx.x, lane = tid & 63, w = tid >> 6;
    const int g = lane >> 4, qi = lane & 15;
    const int srow = lane >> 3, scol = (lane & 7) * 8;

    f32x4 acc[2][4];
#pragma unroll
    for (int mt = 0; mt < 2; ++mt)
#pragma unroll
        for (int nt = 0; nt < 4; ++nt) acc[mt][nt] = f32x4{0.f, 0.f, 0.f, 0.f};

    for (int k0 = 0; k0 < DMODEL; k0 += 64) {
#pragma unroll
        for (int i = 0; i < 4; ++i) {
            int t = w * 4 + i;  // A: 16 chunks of 8 rows
            async16(attn + (size_t)(i0 + 8 * t + srow) * DMODEL + k0 + scol, &A_lds[8 * t][0]);
        }
#pragma unroll
        for (int i = 0; i < 2; ++i) {
            int t = w * 2 + i;  // B: 8 chunks of 8 rows
            async16(WoT + (size_t)(n0 + 8 * t + srow) * DMODEL + k0 + scol, &B_lds[8 * t][0]);
        }
        __syncthreads();
#pragma unroll
        for (int kc = 0; kc < 2; ++kc) {
            short8 a[2], b[4];
#pragma unroll
            for (int mt = 0; mt < 2; ++mt)
                a[mt] = *(const short8*)&A_lds[w * 32 + mt * 16 + qi][kc * 32 + g * 8];
#pragma unroll
            for (int nt = 0; nt < 4; ++nt)
                b[nt] = *(const short8*)&B_lds[nt * 16 + qi][kc * 32 + g * 8];
#pragma unroll
            for (int mt = 0; mt < 2; ++mt)
#pragma unroll
                for (int nt = 0; nt < 4; ++nt)
                    acc[mt][nt] = mfma16(a[mt], b[nt], acc[mt][nt]);
        }
        __syncthreads();
    }

#pragma unroll
    for (int mt = 0; mt < 2; ++mt)
#pragma unroll
        for (int nt = 0; nt < 4; ++nt) {
            int ncol = n0 + nt * 16 + qi;
            float bb = bo[ncol];
#pragma unroll
            for (int r = 0; r < 4; ++r) {
                int i = i0 + w * 32 + mt * 16 + 4 * g + r;
                out[(size_t)i * DMODEL + ncol] = acc[mt][nt][r] + bb;
            }
        }
}

// ---------------------------------------------------------------------------
extern "C" void kernel_launch(void* const* d_in, const int* in_sizes, int n_in,
                              void* d_out, int out_size, void* d_ws, size_t ws_size,
                              hipStream_t stream) {
    const float* Q  = (const float*)d_in[0];
    const float* K  = (const float*)d_in[1];
    const float* V  = (const float*)d_in[2];
    const float* Wq = (const float*)d_in[3];
    const float* bq = (const float*)d_in[4];
    const float* Wk = (const float*)d_in[5];
    const float* bk = (const float*)d_in[6];
    const float* Wv = (const float*)d_in[7];
    const float* bv = (const float*)d_in[8];
    const float* Wo = (const float*)d_in[9];
    const float* bo = (const float*)d_in[10];

    // ws layout (shorts): WT[4M] | q[4M] | k[4M] | vT[4M] | xb[12M]
    // attn output reuses the xb region (xb consumed by qkv_gemm before attn runs)
    const size_t WSZ = (size_t)DMODEL * DMODEL;      // 1M
    const size_t XSZ = (size_t)NB * SEQ * DMODEL;    // 4M
    if (ws_size < (4 * WSZ + 6 * XSZ) * sizeof(short)) return;  // 56 MB

    short* WT      = (short*)d_ws;
    short* q_ws    = WT + 4 * WSZ;
    short* k_ws    = q_ws + XSZ;
    short* vT_ws   = k_ws + XSZ;
    short* xb      = vT_ws + XSZ;
    short* attn_ws = xb;  // reuse

    prep_kernel<<<dim3(12288 + 4096), 256, 0, stream>>>(
        Q, K, V, Wq, Wk, Wv, Wo, xb, WT);
    qkv_gemm_kernel<<<dim3((NB * SEQ) / 128, DMODEL / 128, 3), 256, 0, stream>>>(
        xb, WT, bq, bk, bv, q_ws, k_ws, vT_ws);
    attn_kernel<<<dim3(512), 256, 0, stream>>>(
        q_ws, k_ws, vT_ws, attn_ws);
    oproj_kernel<<<dim3((NB * SEQ) / 128, DMODEL / 64), 256, 0, stream>>>(
        attn_ws, WT + 3 * WSZ, bo, (float*)d_out);
}